// Round 4
// baseline (2236.325 us; speedup 1.0000x reference)
//
#include <hip/hip_runtime.h>
#include <math.h>

// ---- static problem config (matches reference) ----
namespace {
constexpr int N  = 102400;   // nodes
constexpr int E  = 819200;   // edges
constexpr int B_ = 16;       // graphs
constexpr int G  = 72;       // voxel cells per graph (8 x 9)
constexpr int GX = 8;
constexpr int NB = N / 256;  // 400 blocks over nodes
constexpr int EB = E / 256;  // 3200 blocks over edges
}

// ================= CSR build =================

__global__ __launch_bounds__(256) void count_kernel(const int* __restrict__ ei,
                                                    int* __restrict__ cnt) {
  int e = blockIdx.x * 256 + threadIdx.x;
  atomicAdd(&cnt[ei[E + e]], 1);
}

__global__ __launch_bounds__(256) void rcnt_kernel(const int* __restrict__ cnt,
                                                   float* __restrict__ rcnt) {
  int n = blockIdx.x * 256 + threadIdx.x;
  rcnt[n] = 1.0f / (float)max(cnt[n], 1);
}

// per-256-chunk sums of cnt
__global__ __launch_bounds__(256) void reduce_cnt(const int* __restrict__ cnt,
                                                  int* __restrict__ bsum) {
  __shared__ int s[256];
  int i = blockIdx.x * 256 + threadIdx.x;
  s[threadIdx.x] = cnt[i];
  __syncthreads();
  for (int st = 128; st > 0; st >>= 1) {
    if (threadIdx.x < st) s[threadIdx.x] += s[threadIdx.x + st];
    __syncthreads();
  }
  if (threadIdx.x == 0) bsum[blockIdx.x] = s[0];
}

// single-block exclusive scan of the NB block sums
__global__ __launch_bounds__(512) void scan_bsum(const int* __restrict__ bsum,
                                                 int* __restrict__ boff) {
  __shared__ int s[512];
  int i = threadIdx.x;
  int v = (i < NB) ? bsum[i] : 0;
  s[i] = v;
  __syncthreads();
  for (int st = 1; st < 512; st <<= 1) {
    int t = (i >= st) ? s[i - st] : 0;
    __syncthreads();
    s[i] += t;
    __syncthreads();
  }
  if (i < NB) boff[i] = s[i] - v;  // exclusive
}

// rowptr[n] = exclusive scan of cnt; cursor starts equal to rowptr
__global__ __launch_bounds__(256) void write_rowptr(const int* __restrict__ cnt,
                                                    const int* __restrict__ boff,
                                                    int* __restrict__ rowptr,
                                                    int* __restrict__ cursor) {
  __shared__ int s[256];
  int i = blockIdx.x * 256 + threadIdx.x;
  int v = cnt[i];
  s[threadIdx.x] = v;
  __syncthreads();
  for (int st = 1; st < 256; st <<= 1) {
    int t = (threadIdx.x >= st) ? s[threadIdx.x - st] : 0;
    __syncthreads();
    s[threadIdx.x] += t;
    __syncthreads();
  }
  int off = boff[blockIdx.x] + s[threadIdx.x] - v;  // exclusive
  rowptr[i] = off;
  cursor[i] = off;
  if (i == N - 1) rowptr[N] = off + v;
}

// scatter edge records (src + clamped pseudo-coords) into CSR order
__global__ __launch_bounds__(256) void edge_scatter(const int* __restrict__ ei,
                                                    const float* __restrict__ ea,
                                                    int* __restrict__ cursor,
                                                    float4* __restrict__ rec) {
  int e = blockIdx.x * 256 + threadIdx.x;
  int src = ei[e];
  int dst = ei[E + e];
  float u0 = fminf(fmaxf(ea[3 * e + 0], 0.f), 1.f);
  float u1 = fminf(fmaxf(ea[3 * e + 1], 0.f), 1.f);
  float u2 = fminf(fmaxf(ea[3 * e + 2], 0.f), 1.f);
  int slot = atomicAdd(&cursor[dst], 1);
  rec[slot] = make_float4(__int_as_float(src), u0, u1, u2);
}

// ============ bucket-sort nodes by degree (uniform wave trip counts) ============

__global__ __launch_bounds__(256) void hist_kernel(const int* __restrict__ cnt,
                                                   int* __restrict__ hist) {
  int n = blockIdx.x * 256 + threadIdx.x;
  atomicAdd(&hist[min(cnt[n], 63)], 1);
}

__global__ __launch_bounds__(64) void hist_scan(int* __restrict__ hist) {
  __shared__ int s[64];
  int i = threadIdx.x;
  int v = hist[i];
  s[i] = v;
  __syncthreads();
  for (int st = 1; st < 64; st <<= 1) {
    int t = (i >= st) ? s[i - st] : 0;
    __syncthreads();
    s[i] += t;
    __syncthreads();
  }
  hist[i] = s[i] - v;  // exclusive -> becomes cursor
}

__global__ __launch_bounds__(256) void order_kernel(const int* __restrict__ cnt,
                                                    int* __restrict__ hcur,
                                                    int* __restrict__ order) {
  int n = blockIdx.x * 256 + threadIdx.x;
  int pos = atomicAdd(&hcur[min(cnt[n], 63)], 1);
  order[pos] = n;
}

// ================= pooling helper =================
__device__ __forceinline__ void atomicMaxFloat(float* addr, float val) {
  if (val >= 0.f)
    atomicMax(reinterpret_cast<int*>(addr), __float_as_int(val));
  else
    atomicMin(reinterpret_cast<unsigned int*>(addr), __float_as_uint(val));
}

// ================= factored spline conv =================
// out[n] = (1/deg) * sum_k ( sum_{e->n} b_k(e) * x_src(e) ) @ W[k]
// 8 lanes per node; lane l owns spline kernel k=l.
// Phase 1: all 8 lanes walk the node's edge list together (broadcast loads),
//          lane l accumulates agg[ci] = sum_e b_l(e) * x_src[ci]   (CIN regs).
// Phase 2: lane l computes acc[co] = sum_ci agg[ci] * W[l,ci,co] via
//          L1-resident float4 W loads (compile-time offsets, 8 distinct
//          addrs/wave-instr -> 128B broadcast loads).
// Reduce : reduce-and-split shuffle exchange (masks 4,2,1, halving payload);
//          lane l ends holding out slice [l*CPL, (l+1)*CPL).
// Epilogue: mean + ELU (+residual), coalesced slice store or voxel-pool atomics.
template <int CIN, int COUT, bool RES, bool POOL>
__global__ __launch_bounds__(256) void node_conv_fac(
    const float* __restrict__ X, const float* __restrict__ W,
    const float4* __restrict__ rec, const int* __restrict__ rowptr,
    const int* __restrict__ order, const float* __restrict__ rcnt,
    const float* __restrict__ res, float* __restrict__ Y,
    const float* __restrict__ pos, const int* __restrict__ batch,
    float* __restrict__ pooled) {
  int t = blockIdx.x * 256 + threadIdx.x;
  int slot = t >> 3;   // node slot (8 lanes each)
  int l = t & 7;       // lane within node == owned spline kernel k
  int n = order[slot];
  int beg = rowptr[n], end = rowptr[n + 1];

  // ---- phase 1: per-k aggregation over edges ----
  float agg[CIN];
#pragma unroll
  for (int i = 0; i < CIN; i++) agg[i] = 0.f;

  for (int e = beg; e < end; e++) {
    float4 r = rec[e];                 // broadcast across the 8 lanes
    int src = __float_as_int(r.x);
    float f0 = (l & 1) ? r.y : 1.f - r.y;
    float f1 = (l & 2) ? r.z : 1.f - r.z;
    float f2 = (l & 4) ? r.w : 1.f - r.w;
    float bl = f0 * f1 * f2;

    if (CIN == 1) {
      agg[0] = fmaf(bl, X[src], agg[0]);
    } else {
      const float4* xp = reinterpret_cast<const float4*>(X + (size_t)src * CIN);
#pragma unroll
      for (int i = 0; i < CIN / 4; i++) {
        float4 v = xp[i];
        agg[4 * i + 0] = fmaf(bl, v.x, agg[4 * i + 0]);
        agg[4 * i + 1] = fmaf(bl, v.y, agg[4 * i + 1]);
        agg[4 * i + 2] = fmaf(bl, v.z, agg[4 * i + 2]);
        agg[4 * i + 3] = fmaf(bl, v.w, agg[4 * i + 3]);
      }
    }
  }

  // ---- phase 2: per-lane dense GEMM slice  acc += agg @ W[l] ----
  float acc[COUT];
#pragma unroll
  for (int co = 0; co < COUT; co++) acc[co] = 0.f;

  const float4* Wl =
      reinterpret_cast<const float4*>(W + (size_t)l * CIN * COUT);
#pragma unroll 4
  for (int ci = 0; ci < CIN; ci++) {
    float a = agg[ci];
#pragma unroll
    for (int c4 = 0; c4 < COUT / 4; c4++) {
      float4 w4 = Wl[ci * (COUT / 4) + c4];
      acc[4 * c4 + 0] = fmaf(a, w4.x, acc[4 * c4 + 0]);
      acc[4 * c4 + 1] = fmaf(a, w4.y, acc[4 * c4 + 1]);
      acc[4 * c4 + 2] = fmaf(a, w4.z, acc[4 * c4 + 2]);
      acc[4 * c4 + 3] = fmaf(a, w4.w, acc[4 * c4 + 3]);
    }
  }

  // ---- reduce-and-split across the 8 lanes (masks 4,2,1) ----
  // After stage s, lane owns a COUT>>(s+1) slice; final slice starts at l*CPL.
#pragma unroll
  for (int s = 0; s < 3; s++) {
    const int m = 4 >> s;               // 4, 2, 1
    const int half = COUT >> (s + 1);   // COUT/2, /4, /8
    bool up = (l & m) != 0;
#pragma unroll
    for (int i = 0; i < half; i++) {
      float keep = up ? acc[i + half] : acc[i];
      float send = up ? acc[i] : acc[i + half];
      acc[i] = keep + __shfl_xor(send, m, 64);
    }
  }

  constexpr int CPL = COUT / 8;
  float rc = rcnt[n];
  float mv[CPL];
#pragma unroll
  for (int i = 0; i < CPL; i++) {
    float w = acc[i] * rc;
    w = w > 0.f ? w : expm1f(w);
    if (RES) w += res[(size_t)n * COUT + l * CPL + i];
    mv[i] = w;
  }

  if (POOL) {
    int cx = (int)floorf(pos[n * 3 + 0] / 16.0f);
    int cy = (int)floorf(pos[n * 3 + 1] / 12.0f);
    int cl = batch[n] * G + cy * GX + cx;
    float* pr = pooled + cl * 32 + l * CPL;
#pragma unroll
    for (int i = 0; i < CPL; i++) atomicMaxFloat(&pr[i], mv[i]);
  } else {
    float* yp = Y + (size_t)n * COUT + l * CPL;
    if (CPL == 4) {
      *reinterpret_cast<float4*>(yp) = make_float4(mv[0], mv[1], mv[2], mv[3]);
    } else if (CPL == 2) {
      *reinterpret_cast<float2*>(yp) = make_float2(mv[0], mv[1]);
    } else {
      yp[0] = mv[0];
    }
  }
}

// ================= final FC =================
__global__ __launch_bounds__(256) void fc_kernel(const float* __restrict__ pooled,
                                                 const float* __restrict__ fcw,
                                                 float* __restrict__ out) {
  int b = blockIdx.x >> 1;
  int o = blockIdx.x & 1;
  const float* pb = pooled + b * (G * 32);
  float s = 0.f;
  for (int i = threadIdx.x; i < G * 32; i += 256) {
    float v = pb[i];
    v = isfinite(v) ? v : 0.f;  // untouched cells (0xFF memset -> NaN) -> 0
    s += v * fcw[i * 2 + o];
  }
  __shared__ float red[256];
  red[threadIdx.x] = s;
  __syncthreads();
  for (int st = 128; st > 0; st >>= 1) {
    if (threadIdx.x < st) red[threadIdx.x] += red[threadIdx.x + st];
    __syncthreads();
  }
  if (threadIdx.x == 0) out[b * 2 + o] = red[0];
}

extern "C" void kernel_launch(void* const* d_in, const int* in_sizes, int n_in,
                              void* d_out, int out_size, void* d_ws, size_t ws_size,
                              hipStream_t stream) {
  const float* x     = (const float*)d_in[0];
  const float* pos   = (const float*)d_in[1];
  const float* ea    = (const float*)d_in[2];
  const int*   ei    = (const int*)d_in[3];
  const int*   batch = (const int*)d_in[4];
  const float* fcw   = (const float*)d_in[5];
  const float* w1    = (const float*)d_in[6];
  const float* w2    = (const float*)d_in[7];
  const float* w3    = (const float*)d_in[8];
  const float* w4    = (const float*)d_in[9];
  const float* w5    = (const float*)d_in[10];
  const float* w6    = (const float*)d_in[11];
  const float* w7    = (const float*)d_in[12];
  float* out = (float*)d_out;

  // ---- workspace layout (256B-aligned chunks) ----
  char* ws = (char*)d_ws;
  size_t off = 0;
  auto alloc = [&](size_t bytes) {
    size_t p = off;
    off += (bytes + 255) & ~(size_t)255;
    return ws + p;
  };
  float*  rcnt   = (float*)alloc((size_t)N * 4);
  int*    cnt    = (int*)alloc((size_t)N * 4);
  int*    rowptr = (int*)alloc((size_t)(N + 1) * 4);
  int*    cursor = (int*)alloc((size_t)N * 4);
  int*    bsum   = (int*)alloc(512 * 4);
  int*    boff   = (int*)alloc(512 * 4);
  int*    hist   = (int*)alloc(64 * 4);
  int*    order  = (int*)alloc((size_t)N * 4);
  float4* rec    = (float4*)alloc((size_t)E * 16);
  float*  bufA   = (float*)alloc((size_t)N * 32 * 4);
  float*  bufB   = (float*)alloc((size_t)N * 32 * 4);
  float*  bufC   = (float*)alloc((size_t)N * 32 * 4);
  float*  pooled = (float*)alloc((size_t)B_ * G * 32 * 4);

  const int NB8 = N * 8 / 256;  // 3200 blocks for 8-lane-per-node convs

  // ---- CSR build ----
  hipMemsetAsync(cnt, 0, (size_t)N * 4, stream);
  count_kernel<<<EB, 256, 0, stream>>>(ei, cnt);
  rcnt_kernel<<<NB, 256, 0, stream>>>(cnt, rcnt);
  reduce_cnt<<<NB, 256, 0, stream>>>(cnt, bsum);
  scan_bsum<<<1, 512, 0, stream>>>(bsum, boff);
  write_rowptr<<<NB, 256, 0, stream>>>(cnt, boff, rowptr, cursor);
  edge_scatter<<<EB, 256, 0, stream>>>(ei, ea, cursor, rec);

  // ---- degree bucket sort ----
  hipMemsetAsync(hist, 0, 64 * 4, stream);
  hist_kernel<<<NB, 256, 0, stream>>>(cnt, hist);
  hist_scan<<<1, 64, 0, stream>>>(hist);
  order_kernel<<<NB, 256, 0, stream>>>(cnt, hist, order);

  // ---- pooled init (must precede conv7) ----
  hipMemsetAsync(pooled, 0xFF, (size_t)B_ * G * 32 * 4, stream);

  // ---- conv ladder (factored, lane-owns-k) ----
  // conv1: 1->8    x -> A
  node_conv_fac<1, 8, false, false><<<NB8, 256, 0, stream>>>(
      x, w1, rec, rowptr, order, rcnt, nullptr, bufA, nullptr, nullptr, nullptr);
  // conv2: 8->16   A -> B   (B = h_sc1)
  node_conv_fac<8, 16, false, false><<<NB8, 256, 0, stream>>>(
      bufA, w2, rec, rowptr, order, rcnt, nullptr, bufB, nullptr, nullptr, nullptr);
  // conv3: 16->16  B -> C
  node_conv_fac<16, 16, false, false><<<NB8, 256, 0, stream>>>(
      bufB, w3, rec, rowptr, order, rcnt, nullptr, bufC, nullptr, nullptr, nullptr);
  // conv4: 16->16  C -> A, + residual B
  node_conv_fac<16, 16, true, false><<<NB8, 256, 0, stream>>>(
      bufC, w4, rec, rowptr, order, rcnt, bufB, bufA, nullptr, nullptr, nullptr);
  // conv5: 16->32  A -> C   (C = h_sc2)
  node_conv_fac<16, 32, false, false><<<NB8, 256, 0, stream>>>(
      bufA, w5, rec, rowptr, order, rcnt, nullptr, bufC, nullptr, nullptr, nullptr);
  // conv6: 32->32  C -> B
  node_conv_fac<32, 32, false, false><<<NB8, 256, 0, stream>>>(
      bufC, w6, rec, rowptr, order, rcnt, nullptr, bufB, nullptr, nullptr, nullptr);
  // conv7: 32->32  B -> (pool), + residual C
  node_conv_fac<32, 32, true, true><<<NB8, 256, 0, stream>>>(
      bufB, w7, rec, rowptr, order, rcnt, bufC, nullptr, pos, batch, pooled);

  // ---- FC ----
  fc_kernel<<<B_ * 2, 256, 0, stream>>>(pooled, fcw, out);
}